// Round 3
// baseline (7302.765 us; speedup 1.0000x reference)
//
#include <hip/hip_runtime.h>

#define NN 50000
#define NE 800000

static_assert(NE % 64 == 0, "edge tiles exact");

__device__ __forceinline__ float4 ld4(const float* p) { return *(const float4*)p; }
__device__ __forceinline__ void st4(float* p, float4 v) { *(float4*)p = v; }

// ---------------------------------------------------------------------------
// Generic fp32 tile GEMM: acc[r][j] += sum_k At[row][k] * W[k][c0+cg*8+j]
// 256 threads: cg = tid&15 (8-col group), rg = tid>>4; row = rg + 16*r.
// At is LDS with row stride AST (132 or 260 -> <=2-way bank conflict, free).
// ---------------------------------------------------------------------------
template<int RPT, int KTOT, int AST>
__device__ __forceinline__ void gemm_f32(const float* At, const float* __restrict__ W,
                                         int wstride, int c0, int cg, int rg,
                                         float acc[RPT][8])
{
  const float* wbase = W + c0 + cg * 8;
#pragma unroll 4
  for (int k = 0; k < KTOT; k += 4) {
    float w[4][8];
#pragma unroll
    for (int kk = 0; kk < 4; ++kk) {
      const float* wp = wbase + (size_t)(k + kk) * wstride;
      float4 wa = ld4(wp), wb = ld4(wp + 4);
      w[kk][0] = wa.x; w[kk][1] = wa.y; w[kk][2] = wa.z; w[kk][3] = wa.w;
      w[kk][4] = wb.x; w[kk][5] = wb.y; w[kk][6] = wb.z; w[kk][7] = wb.w;
    }
#pragma unroll
    for (int r = 0; r < RPT; ++r) {
      float4 a = ld4(At + (rg + 16 * r) * AST + k);
      float av[4] = {a.x, a.y, a.z, a.w};
#pragma unroll
      for (int kk = 0; kk < 4; ++kk)
#pragma unroll
        for (int j = 0; j < 8; ++j)
          acc[r][j] = fmaf(av[kk], w[kk][j], acc[r][j]);
    }
  }
}

// Column-stat reduce: per-thread csum/csq (8 cols each) -> double atomics.
// red is LDS [16][128] (may alias a dead buffer; leading sync makes it safe).
__device__ __forceinline__ void col_stats_reduce(float* red, const float csum[8], const float csq[8],
                                                 int cg, int rg, int tid,
                                                 double* gsum, double* gsq)
{
  __syncthreads();
#pragma unroll
  for (int j = 0; j < 8; ++j) red[rg * 128 + cg * 8 + j] = csum[j];
  __syncthreads();
  if (tid < 128) {
    float s = 0.f;
#pragma unroll
    for (int g = 0; g < 16; ++g) s += red[g * 128 + tid];
    atomicAdd(&gsum[tid], (double)s);
  }
  __syncthreads();
#pragma unroll
  for (int j = 0; j < 8; ++j) red[rg * 128 + cg * 8 + j] = csq[j];
  __syncthreads();
  if (tid < 128) {
    float s = 0.f;
#pragma unroll
    for (int g = 0; g < 16; ++g) s += red[g * 128 + tid];
    atomicAdd(&gsq[tid], (double)s);
  }
}

// ---------------------------------------------------------------------------
// Fused QKV: one h-tile load, three GEMMs (Q,K,V)
// ---------------------------------------------------------------------------
__global__ __launch_bounds__(256) void k_qkv(const float* __restrict__ h,
    const float* __restrict__ Wq, const float* __restrict__ Wk, const float* __restrict__ Wv,
    float* __restrict__ Q, float* __restrict__ K, float* __restrict__ V)
{
  __shared__ float At[64 * 132];
  const int tid = threadIdx.x;
  const int r0 = blockIdx.x * 64;

#pragma unroll
  for (int i = 0; i < 8; ++i) {
    int lin = tid + i * 256;
    int row = lin >> 5, c4 = (lin & 31) * 4;
    int gr = r0 + row;
    float4 v = make_float4(0.f, 0.f, 0.f, 0.f);
    if (gr < NN) v = ld4(h + (size_t)gr * 128 + c4);
    st4(At + row * 132 + c4, v);
  }
  __syncthreads();
  const int cg = tid & 15, rg = tid >> 4;

#pragma unroll 1
  for (int ov = 0; ov < 3; ++ov) {
    const float* W = (ov == 0) ? Wq : (ov == 1) ? Wk : Wv;
    float* Y = (ov == 0) ? Q : (ov == 1) ? K : V;
    float acc[4][8] = {};
    gemm_f32<4, 128, 132>(At, W, 128, 0, cg, rg, acc);
#pragma unroll
    for (int r = 0; r < 4; ++r) {
      int row = r0 + rg + 16 * r;
      if (row < NN) {
        st4(Y + (size_t)row * 128 + cg * 8,     make_float4(acc[r][0], acc[r][1], acc[r][2], acc[r][3]));
        st4(Y + (size_t)row * 128 + cg * 8 + 4, make_float4(acc[r][4], acc[r][5], acc[r][6], acc[r][7]));
      }
    }
  }
}

// ---------------------------------------------------------------------------
// Edge kernel: pe = e@We; score = K[src]*Q[dst]*pe/4; s = exp(clip(sum_h));
// atomics: wV[dst] += V[src]*s, z[dst] += s;
// e2 = e + score@O_e_w + O_e_b -> out_e (pre-BN1) + bn1e stats.
// ---------------------------------------------------------------------------
__global__ __launch_bounds__(256) void k_edge(
    const float* __restrict__ e, const float* __restrict__ We,
    const float* __restrict__ Oew, const float* __restrict__ Oeb,
    const float* __restrict__ Q, const float* __restrict__ K, const float* __restrict__ V,
    const int* __restrict__ src, const int* __restrict__ dst,
    float* __restrict__ wV, float* __restrict__ z,
    float* __restrict__ out_e, double* __restrict__ bn_sum, double* __restrict__ bn_sq)
{
  __shared__ float et[64 * 132];
  __shared__ float st[64 * 132];
  __shared__ float sums8[64][16];
  __shared__ int sds[64];
  __shared__ int sdd[64];

  const int tid = threadIdx.x;
  const int e0 = blockIdx.x * 64;

#pragma unroll
  for (int i = 0; i < 8; ++i) {
    int lin = tid + i * 256;
    int row = lin >> 5, c4 = (lin & 31) * 4;
    st4(et + row * 132 + c4, ld4(e + (size_t)(e0 + row) * 128 + c4));
  }
  if (tid < 64) sds[tid] = src[e0 + tid];
  else if (tid < 128) sdd[tid - 64] = dst[e0 + tid - 64];
  __syncthreads();

  const int cg = tid & 15, rg = tid >> 4;
  const int c0 = cg * 8;

  float pe[4][8] = {};
  gemm_f32<4, 128, 132>(et, We, 128, 0, cg, rg, pe);

  // score + per-cg partial sums
#pragma unroll
  for (int r = 0; r < 4; ++r) {
    int lrow = rg + 16 * r;
    int sn = sds[lrow], dn = sdd[lrow];
    float4 k1 = ld4(K + (size_t)sn * 128 + c0), k2 = ld4(K + (size_t)sn * 128 + c0 + 4);
    float4 q1 = ld4(Q + (size_t)dn * 128 + c0), q2 = ld4(Q + (size_t)dn * 128 + c0 + 4);
    float g[8] = {k1.x * q1.x, k1.y * q1.y, k1.z * q1.z, k1.w * q1.w,
                  k2.x * q2.x, k2.y * q2.y, k2.z * q2.z, k2.w * q2.w};
    float part = 0.f;
    float sc[8];
#pragma unroll
    for (int j = 0; j < 8; ++j) { sc[j] = pe[r][j] * g[j] * 0.25f; part += sc[j]; }
    sums8[lrow][cg] = part;
    st4(st + lrow * 132 + c0,     make_float4(sc[0], sc[1], sc[2], sc[3]));
    st4(st + lrow * 132 + c0 + 4, make_float4(sc[4], sc[5], sc[6], sc[7]));
  }
  __syncthreads();

  // attention scatter (atomics)
#pragma unroll
  for (int r = 0; r < 4; ++r) {
    int lrow = rg + 16 * r;
    int hb = cg & ~1;
    float ssum = sums8[lrow][hb] + sums8[lrow][hb + 1];
    float sval = expf(fminf(fmaxf(ssum, -5.f), 5.f));
    int sn = sds[lrow], dn = sdd[lrow];
    float4 v1 = ld4(V + (size_t)sn * 128 + c0), v2 = ld4(V + (size_t)sn * 128 + c0 + 4);
    float* wp = wV + (size_t)dn * 128 + c0;
    atomicAdd(wp + 0, v1.x * sval); atomicAdd(wp + 1, v1.y * sval);
    atomicAdd(wp + 2, v1.z * sval); atomicAdd(wp + 3, v1.w * sval);
    atomicAdd(wp + 4, v2.x * sval); atomicAdd(wp + 5, v2.y * sval);
    atomicAdd(wp + 6, v2.z * sval); atomicAdd(wp + 7, v2.w * sval);
    if ((cg & 1) == 0) atomicAdd(z + (size_t)dn * 8 + (cg >> 1), sval);
  }

  // e2 = e + score @ O_e_w + O_e_b
  float acc[4][8] = {};
  gemm_f32<4, 128, 132>(st, Oew, 128, 0, cg, rg, acc);

  float bias[8];
#pragma unroll
  for (int j = 0; j < 8; ++j) bias[j] = Oeb[c0 + j];

  float csum[8] = {}, csq[8] = {};
#pragma unroll
  for (int r = 0; r < 4; ++r) {
    int lrow = rg + 16 * r;
    size_t ge = (size_t)(e0 + lrow);
    float val[8];
#pragma unroll
    for (int j = 0; j < 8; ++j) {
      val[j] = et[lrow * 132 + c0 + j] + acc[r][j] + bias[j];
      csum[j] += val[j];
      csq[j] += val[j] * val[j];
    }
    st4(out_e + ge * 128 + c0,     make_float4(val[0], val[1], val[2], val[3]));
    st4(out_e + ge * 128 + c0 + 4, make_float4(val[4], val[5], val[6], val[7]));
  }
  // red aliases st (dead after GEMM2; reduce has leading sync)
  col_stats_reduce(st, csum, csq, cg, rg, tid, bn_sum, bn_sq);
}

// ---------------------------------------------------------------------------
// Node kernel: h_attn = wV/(z+1e-6); h2 = h + h_attn@O_h_w + O_h_b -> out_h
// ---------------------------------------------------------------------------
__global__ __launch_bounds__(256) void k_node(
    const float* __restrict__ h, const float* __restrict__ wV, const float* __restrict__ z,
    const float* __restrict__ Ohw, const float* __restrict__ Ohb,
    float* __restrict__ out_h, double* __restrict__ bn_sum, double* __restrict__ bn_sq)
{
  __shared__ float At[64 * 132];
  __shared__ float red[16 * 128];
  const int tid = threadIdx.x;
  const int r0 = blockIdx.x * 64;

#pragma unroll
  for (int i = 0; i < 8; ++i) {
    int lin = tid + i * 256;
    int row = lin >> 5, c4 = (lin & 31) * 4;
    int gr = r0 + row;
    float4 v = make_float4(0.f, 0.f, 0.f, 0.f);
    if (gr < NN) {
      float4 wv = ld4(wV + (size_t)gr * 128 + c4);
      float inv = 1.f / (z[(size_t)gr * 8 + (c4 >> 4)] + 1e-6f);
      v = make_float4(wv.x * inv, wv.y * inv, wv.z * inv, wv.w * inv);
    }
    st4(At + row * 132 + c4, v);
  }
  __syncthreads();
  const int cg = tid & 15, rg = tid >> 4;
  const int c0 = cg * 8;
  float acc[4][8] = {};
  gemm_f32<4, 128, 132>(At, Ohw, 128, 0, cg, rg, acc);

  float bias[8];
#pragma unroll
  for (int j = 0; j < 8; ++j) bias[j] = Ohb[c0 + j];

  float csum[8] = {}, csq[8] = {};
#pragma unroll
  for (int r = 0; r < 4; ++r) {
    int row = r0 + rg + 16 * r;
    if (row < NN) {
      float4 h1 = ld4(h + (size_t)row * 128 + c0), h2 = ld4(h + (size_t)row * 128 + c0 + 4);
      float hv[8] = {h1.x, h1.y, h1.z, h1.w, h2.x, h2.y, h2.z, h2.w};
      float val[8];
#pragma unroll
      for (int j = 0; j < 8; ++j) {
        val[j] = hv[j] + acc[r][j] + bias[j];
        csum[j] += val[j];
        csq[j] += val[j] * val[j];
      }
      st4(out_h + (size_t)row * 128 + c0,     make_float4(val[0], val[1], val[2], val[3]));
      st4(out_h + (size_t)row * 128 + c0 + 4, make_float4(val[4], val[5], val[6], val[7]));
    }
  }
  col_stats_reduce(red, csum, csq, cg, rg, tid, bn_sum, bn_sq);
}

// ---------------------------------------------------------------------------
// BN finalize: scale = g*rsqrt(var+eps), shift = b - mean*scale  (h set + e set)
// ---------------------------------------------------------------------------
__global__ void k_bnfin(const double* sum_h, const double* sq_h,
                        const float* g_h, const float* b_h, float cnt_h,
                        float* sc_h, float* sh_h,
                        const double* sum_e, const double* sq_e,
                        const float* g_e, const float* b_e, float cnt_e,
                        float* sc_e, float* sh_e)
{
  int t = threadIdx.x;
  if (t < 128) {
    float m = (float)(sum_h[t] / (double)cnt_h);
    float v = (float)(sq_h[t] / (double)cnt_h) - m * m;
    float is = 1.f / sqrtf(v + 1e-5f);
    float s = is * g_h[t];
    sc_h[t] = s; sh_h[t] = b_h[t] - m * s;
  } else if (t < 256) {
    int c = t - 128;
    float m = (float)(sum_e[c] / (double)cnt_e);
    float v = (float)(sq_e[c] / (double)cnt_e) - m * m;
    float is = 1.f / sqrtf(v + 1e-5f);
    float s = is * g_e[c];
    sc_e[c] = s; sh_e[c] = b_e[c] - m * s;
  }
}

// ---------------------------------------------------------------------------
// FFN: x = BN1(row); t = x + relu(x@W1+b1)@W2+b2  (in-place on io) + bn2 stats
// 32-row tiles. red aliases ut -> LDS ~50 KB -> 3 blocks/CU.
// ---------------------------------------------------------------------------
__global__ __launch_bounds__(256) void k_ffn(
    float* __restrict__ io,
    const float* __restrict__ sc1, const float* __restrict__ sh1,
    const float* __restrict__ W1, const float* __restrict__ b1,
    const float* __restrict__ W2, const float* __restrict__ b2,
    double* __restrict__ bn_sum, double* __restrict__ bn_sq, int Rtot)
{
  __shared__ float xt[32 * 132];
  __shared__ float ut[32 * 260];
  const int tid = threadIdx.x;
  const int r0 = blockIdx.x * 32;

#pragma unroll
  for (int i = 0; i < 4; ++i) {
    int lin = tid + i * 256;
    int row = lin >> 5, c4 = (lin & 31) * 4;
    int gr = r0 + row;
    float4 v = make_float4(0.f, 0.f, 0.f, 0.f);
    if (gr < Rtot) {
      float4 x = ld4(io + (size_t)gr * 128 + c4);
      float4 s = ld4(sc1 + c4), sh = ld4(sh1 + c4);
      v = make_float4(fmaf(x.x, s.x, sh.x), fmaf(x.y, s.y, sh.y),
                      fmaf(x.z, s.z, sh.z), fmaf(x.w, s.w, sh.w));
    }
    st4(xt + row * 132 + c4, v);
  }
  __syncthreads();
  const int cg = tid & 15, rg = tid >> 4;
  const int c0 = cg * 8;

  // GEMM1: u = relu(x@W1 + b1), 256 cols in two halves
#pragma unroll 1
  for (int ch = 0; ch < 2; ++ch) {
    float acc[2][8] = {};
    gemm_f32<2, 128, 132>(xt, W1, 256, ch * 128, cg, rg, acc);
#pragma unroll
    for (int r = 0; r < 2; ++r) {
      int lrow = rg + 16 * r;
#pragma unroll
      for (int j = 0; j < 8; ++j) {
        float uv = acc[r][j] + b1[ch * 128 + c0 + j];
        ut[lrow * 260 + ch * 128 + c0 + j] = fmaxf(uv, 0.f);
      }
    }
  }
  __syncthreads();

  // GEMM2: t = x + u@W2 + b2
  float acc[2][8] = {};
  gemm_f32<2, 256, 260>(ut, W2, 128, 0, cg, rg, acc);

  float bias[8];
#pragma unroll
  for (int j = 0; j < 8; ++j) bias[j] = b2[c0 + j];

  float csum[8] = {}, csq[8] = {};
#pragma unroll
  for (int r = 0; r < 2; ++r) {
    int lrow = rg + 16 * r;
    int gr = r0 + lrow;
    if (gr < Rtot) {
      float val[8];
#pragma unroll
      for (int j = 0; j < 8; ++j) {
        val[j] = xt[lrow * 132 + c0 + j] + acc[r][j] + bias[j];
        csum[j] += val[j];
        csq[j] += val[j] * val[j];
      }
      st4(io + (size_t)gr * 128 + c0,     make_float4(val[0], val[1], val[2], val[3]));
      st4(io + (size_t)gr * 128 + c0 + 4, make_float4(val[4], val[5], val[6], val[7]));
    }
  }
  // red aliases ut (dead after GEMM2; reduce has leading sync)
  col_stats_reduce(ut, csum, csq, cg, rg, tid, bn_sum, bn_sq);
}

// ---------------------------------------------------------------------------
// Final BN apply for both h and e ranges (in place, elementwise), one launch
// ---------------------------------------------------------------------------
__global__ void k_bnapply2(float* __restrict__ oh, float* __restrict__ oe,
                           const float* __restrict__ sch, const float* __restrict__ shh,
                           const float* __restrict__ sce, const float* __restrict__ she)
{
  const int n4h = NN * 32;
  const int n4t = (NN + NE) * 32;
  for (int i = blockIdx.x * blockDim.x + threadIdx.x; i < n4t; i += gridDim.x * blockDim.x) {
    int c4 = (i & 31) * 4;
    float* p;
    const float* sc;
    const float* sh;
    if (i < n4h) { p = oh + (size_t)i * 4; sc = sch; sh = shh; }
    else { p = oe + (size_t)(i - n4h) * 4; sc = sce; sh = she; }
    float4 v = ld4(p);
    float4 s = ld4(sc + c4), b = ld4(sh + c4);
    st4(p, make_float4(fmaf(v.x, s.x, b.x), fmaf(v.y, s.y, b.y),
                       fmaf(v.z, s.z, b.z), fmaf(v.w, s.w, b.w)));
  }
}

// ---------------------------------------------------------------------------
extern "C" void kernel_launch(void* const* d_in, const int* in_sizes, int n_in,
                              void* d_out, int out_size, void* d_ws, size_t ws_size,
                              hipStream_t stream)
{
  const float* h    = (const float*)d_in[0];
  const float* e    = (const float*)d_in[1];
  const float* Wq   = (const float*)d_in[2];
  const float* Wk   = (const float*)d_in[3];
  const float* Wv   = (const float*)d_in[4];
  const float* We   = (const float*)d_in[5];
  const float* Ohw  = (const float*)d_in[6];
  const float* Ohb  = (const float*)d_in[7];
  const float* Oew  = (const float*)d_in[8];
  const float* Oeb  = (const float*)d_in[9];
  const float* bn1h_g = (const float*)d_in[10];
  const float* bn1h_b = (const float*)d_in[11];
  const float* bn1e_g = (const float*)d_in[12];
  const float* bn1e_b = (const float*)d_in[13];
  const float* fhw1 = (const float*)d_in[14];
  const float* fhb1 = (const float*)d_in[15];
  const float* fhw2 = (const float*)d_in[16];
  const float* fhb2 = (const float*)d_in[17];
  const float* few1 = (const float*)d_in[18];
  const float* feb1 = (const float*)d_in[19];
  const float* few2 = (const float*)d_in[20];
  const float* feb2 = (const float*)d_in[21];
  const float* bn2h_g = (const float*)d_in[22];
  const float* bn2h_b = (const float*)d_in[23];
  const float* bn2e_g = (const float*)d_in[24];
  const float* bn2e_b = (const float*)d_in[25];
  const int* src = (const int*)d_in[26];
  const int* dst = (const int*)d_in[27];

  float* out_h = (float*)d_out;                       // [NN*128] pre-BN scratch then h3
  float* out_e = (float*)d_out + (size_t)NN * 128;    // [NE*128] pre-BN scratch then e3

  float* ws = (float*)d_ws;
  float* Q   = ws;
  float* Kp  = Q  + (size_t)NN * 128;
  float* Vp  = Kp + (size_t)NN * 128;
  float* wV  = Vp + (size_t)NN * 128;
  float* z   = wV + (size_t)NN * 128;
  double* stats = (double*)(z + (size_t)NN * 8);      // byte offset divisible by 8
  double* bn1h_sum = stats;        double* bn1h_sq = stats + 128;
  double* bn1e_sum = stats + 256;  double* bn1e_sq = stats + 384;
  double* bn2h_sum = stats + 512;  double* bn2h_sq = stats + 640;
  double* bn2e_sum = stats + 768;  double* bn2e_sq = stats + 896;
  float* par = (float*)(stats + 1024);
  float* sc1h = par;        float* sh1h = par + 128;
  float* sc1e = par + 256;  float* sh1e = par + 384;
  float* sc2h = par + 512;  float* sh2h = par + 640;
  float* sc2e = par + 768;  float* sh2e = par + 896;

  // zero accumulators: wV + z + stats(1024 doubles)
  size_t zero_bytes = ((size_t)NN * 128 + (size_t)NN * 8) * sizeof(float) + 1024 * sizeof(double);
  hipMemsetAsync(wV, 0, zero_bytes, stream);

  const int nb_n64 = (NN + 63) / 64;       // 782
  const int nb_e64 = NE / 64;              // 12500
  const int nb_n32 = (NN + 31) / 32;       // 1563
  const int nb_e32 = NE / 32;              // 25000

  k_qkv<<<nb_n64, 256, 0, stream>>>(h, Wq, Wk, Wv, Q, Kp, Vp);

  k_edge<<<nb_e64, 256, 0, stream>>>(e, We, Oew, Oeb, Q, Kp, Vp, src, dst,
                                     wV, z, out_e, bn1e_sum, bn1e_sq);

  k_node<<<nb_n64, 256, 0, stream>>>(h, wV, z, Ohw, Ohb, out_h, bn1h_sum, bn1h_sq);

  k_bnfin<<<1, 256, 0, stream>>>(bn1h_sum, bn1h_sq, bn1h_g, bn1h_b, (float)NN, sc1h, sh1h,
                                 bn1e_sum, bn1e_sq, bn1e_g, bn1e_b, (float)NE, sc1e, sh1e);

  k_ffn<<<nb_n32, 256, 0, stream>>>(out_h, sc1h, sh1h, fhw1, fhb1, fhw2, fhb2,
                                    bn2h_sum, bn2h_sq, NN);
  k_ffn<<<nb_e32, 256, 0, stream>>>(out_e, sc1e, sh1e, few1, feb1, few2, feb2,
                                    bn2e_sum, bn2e_sq, NE);

  k_bnfin<<<1, 256, 0, stream>>>(bn2h_sum, bn2h_sq, bn2h_g, bn2h_b, (float)NN, sc2h, sh2h,
                                 bn2e_sum, bn2e_sq, bn2e_g, bn2e_b, (float)NE, sc2e, sh2e);

  k_bnapply2<<<2048, 256, 0, stream>>>(out_h, out_e, sc2h, sh2h, sc2e, sh2e);
}

// Round 4
// 5204.499 us; speedup vs baseline: 1.4032x; 1.4032x over previous
//
#include <hip/hip_runtime.h>

#define NN 50000
#define NE 800000
#define SCAN_CHUNKS 196   // ceil(NN/256)

static_assert(NE % 64 == 0, "edge tiles exact");
static_assert((NN + 255) / 256 == SCAN_CHUNKS, "scan chunk count");

__device__ __forceinline__ float4 ld4(const float* p) { return *(const float4*)p; }
__device__ __forceinline__ void st4(float* p, float4 v) { *(float4*)p = v; }

// ---------------------------------------------------------------------------
// Generic fp32 tile GEMM: acc[r][j] += sum_k At[row][k] * W[k][c0+cg*8+j]
// 256 threads: cg = tid&15 (8-col group), rg = tid>>4; row = rg + 16*r.
// At is LDS with row stride AST (132 or 260 -> <=2-way bank conflict, free).
// ---------------------------------------------------------------------------
template<int RPT, int KTOT, int AST>
__device__ __forceinline__ void gemm_f32(const float* At, const float* __restrict__ W,
                                         int wstride, int c0, int cg, int rg,
                                         float acc[RPT][8])
{
  const float* wbase = W + c0 + cg * 8;
#pragma unroll 4
  for (int k = 0; k < KTOT; k += 4) {
    float w[4][8];
#pragma unroll
    for (int kk = 0; kk < 4; ++kk) {
      const float* wp = wbase + (size_t)(k + kk) * wstride;
      float4 wa = ld4(wp), wb = ld4(wp + 4);
      w[kk][0] = wa.x; w[kk][1] = wa.y; w[kk][2] = wa.z; w[kk][3] = wa.w;
      w[kk][4] = wb.x; w[kk][5] = wb.y; w[kk][6] = wb.z; w[kk][7] = wb.w;
    }
#pragma unroll
    for (int r = 0; r < RPT; ++r) {
      float4 a = ld4(At + (rg + 16 * r) * AST + k);
      float av[4] = {a.x, a.y, a.z, a.w};
#pragma unroll
      for (int kk = 0; kk < 4; ++kk)
#pragma unroll
        for (int j = 0; j < 8; ++j)
          acc[r][j] = fmaf(av[kk], w[kk][j], acc[r][j]);
    }
  }
}

// Column-stat reduce: per-thread csum/csq (8 cols each) -> double atomics.
// red is LDS [16][128] (may alias a dead buffer; leading sync makes it safe).
__device__ __forceinline__ void col_stats_reduce(float* red, const float csum[8], const float csq[8],
                                                 int cg, int rg, int tid,
                                                 double* gsum, double* gsq)
{
  __syncthreads();
#pragma unroll
  for (int j = 0; j < 8; ++j) red[rg * 128 + cg * 8 + j] = csum[j];
  __syncthreads();
  if (tid < 128) {
    float s = 0.f;
#pragma unroll
    for (int g = 0; g < 16; ++g) s += red[g * 128 + tid];
    atomicAdd(&gsum[tid], (double)s);
  }
  __syncthreads();
#pragma unroll
  for (int j = 0; j < 8; ++j) red[rg * 128 + cg * 8 + j] = csq[j];
  __syncthreads();
  if (tid < 128) {
    float s = 0.f;
#pragma unroll
    for (int g = 0; g < 16; ++g) s += red[g * 128 + tid];
    atomicAdd(&gsq[tid], (double)s);
  }
}

// ---------------------------------------------------------------------------
// Fused QKV: one h-tile load, three GEMMs (Q,K,V)
// ---------------------------------------------------------------------------
__global__ __launch_bounds__(256) void k_qkv(const float* __restrict__ h,
    const float* __restrict__ Wq, const float* __restrict__ Wk, const float* __restrict__ Wv,
    float* __restrict__ Q, float* __restrict__ K, float* __restrict__ V)
{
  __shared__ float At[64 * 132];
  const int tid = threadIdx.x;
  const int r0 = blockIdx.x * 64;

#pragma unroll
  for (int i = 0; i < 8; ++i) {
    int lin = tid + i * 256;
    int row = lin >> 5, c4 = (lin & 31) * 4;
    int gr = r0 + row;
    float4 v = make_float4(0.f, 0.f, 0.f, 0.f);
    if (gr < NN) v = ld4(h + (size_t)gr * 128 + c4);
    st4(At + row * 132 + c4, v);
  }
  __syncthreads();
  const int cg = tid & 15, rg = tid >> 4;

#pragma unroll 1
  for (int ov = 0; ov < 3; ++ov) {
    const float* W = (ov == 0) ? Wq : (ov == 1) ? Wk : Wv;
    float* Y = (ov == 0) ? Q : (ov == 1) ? K : V;
    float acc[4][8] = {};
    gemm_f32<4, 128, 132>(At, W, 128, 0, cg, rg, acc);
#pragma unroll
    for (int r = 0; r < 4; ++r) {
      int row = r0 + rg + 16 * r;
      if (row < NN) {
        st4(Y + (size_t)row * 128 + cg * 8,     make_float4(acc[r][0], acc[r][1], acc[r][2], acc[r][3]));
        st4(Y + (size_t)row * 128 + cg * 8 + 4, make_float4(acc[r][4], acc[r][5], acc[r][6], acc[r][7]));
      }
    }
  }
}

// ---------------------------------------------------------------------------
// Edge kernel (NO scatter): pe = e@We; score = K[src]*Q[dst]*pe/4;
// s = exp(clip(per-head sum)) -> s_buf[E][8];
// e2 = e + score@O_e_w + O_e_b -> out_e (pre-BN1) + bn1e stats.
// Score tile overwrites et (regs carry it across a barrier); e reloaded from
// global in epilogue. LDS ~37.5 KB -> 4 blocks/CU.
// ---------------------------------------------------------------------------
__global__ __launch_bounds__(256) void k_edge(
    const float* __restrict__ e, const float* __restrict__ We,
    const float* __restrict__ Oew, const float* __restrict__ Oeb,
    const float* __restrict__ Q, const float* __restrict__ K,
    const int* __restrict__ src, const int* __restrict__ dst,
    float* __restrict__ s_buf,
    float* __restrict__ out_e, double* __restrict__ bn_sum, double* __restrict__ bn_sq)
{
  __shared__ float et[64 * 132];
  __shared__ float sums8[64][16];
  __shared__ int sds[64];
  __shared__ int sdd[64];

  const int tid = threadIdx.x;
  const int e0 = blockIdx.x * 64;

#pragma unroll
  for (int i = 0; i < 8; ++i) {
    int lin = tid + i * 256;
    int row = lin >> 5, c4 = (lin & 31) * 4;
    st4(et + row * 132 + c4, ld4(e + (size_t)(e0 + row) * 128 + c4));
  }
  if (tid < 64) sds[tid] = src[e0 + tid];
  else if (tid < 128) sdd[tid - 64] = dst[e0 + tid - 64];
  __syncthreads();

  const int cg = tid & 15, rg = tid >> 4;
  const int c0 = cg * 8;

  float pe[4][8] = {};
  gemm_f32<4, 128, 132>(et, We, 128, 0, cg, rg, pe);

  // score (kept in regs) + per-cg partial sums
  float sc[4][8];
#pragma unroll
  for (int r = 0; r < 4; ++r) {
    int lrow = rg + 16 * r;
    int sn = sds[lrow], dn = sdd[lrow];
    float4 k1 = ld4(K + (size_t)sn * 128 + c0), k2 = ld4(K + (size_t)sn * 128 + c0 + 4);
    float4 q1 = ld4(Q + (size_t)dn * 128 + c0), q2 = ld4(Q + (size_t)dn * 128 + c0 + 4);
    float g[8] = {k1.x * q1.x, k1.y * q1.y, k1.z * q1.z, k1.w * q1.w,
                  k2.x * q2.x, k2.y * q2.y, k2.z * q2.z, k2.w * q2.w};
    float part = 0.f;
#pragma unroll
    for (int j = 0; j < 8; ++j) { sc[r][j] = pe[r][j] * g[j] * 0.25f; part += sc[r][j]; }
    sums8[lrow][cg] = part;
  }
  __syncthreads();  // sums8 ready; all et (pe-GEMM) reads done

  // write per-head s to global; overwrite et with score tile
#pragma unroll
  for (int r = 0; r < 4; ++r) {
    int lrow = rg + 16 * r;
    if ((cg & 1) == 0) {
      float ssum = sums8[lrow][cg] + sums8[lrow][cg + 1];
      float sval = expf(fminf(fmaxf(ssum, -5.f), 5.f));
      s_buf[(size_t)(e0 + lrow) * 8 + (cg >> 1)] = sval;
    }
    st4(et + lrow * 132 + c0,     make_float4(sc[r][0], sc[r][1], sc[r][2], sc[r][3]));
    st4(et + lrow * 132 + c0 + 4, make_float4(sc[r][4], sc[r][5], sc[r][6], sc[r][7]));
  }
  __syncthreads();  // score tile ready

  // e2 = e + score @ O_e_w + O_e_b   (e reloaded from global)
  float acc[4][8] = {};
  gemm_f32<4, 128, 132>(et, Oew, 128, 0, cg, rg, acc);

  float bias[8];
#pragma unroll
  for (int j = 0; j < 8; ++j) bias[j] = Oeb[c0 + j];

  float csum[8] = {}, csq[8] = {};
#pragma unroll
  for (int r = 0; r < 4; ++r) {
    int lrow = rg + 16 * r;
    size_t ge = (size_t)(e0 + lrow);
    float4 e1 = ld4(e + ge * 128 + c0), e2v = ld4(e + ge * 128 + c0 + 4);
    float ev[8] = {e1.x, e1.y, e1.z, e1.w, e2v.x, e2v.y, e2v.z, e2v.w};
    float val[8];
#pragma unroll
    for (int j = 0; j < 8; ++j) {
      val[j] = ev[j] + acc[r][j] + bias[j];
      csum[j] += val[j];
      csq[j] += val[j] * val[j];
    }
    st4(out_e + ge * 128 + c0,     make_float4(val[0], val[1], val[2], val[3]));
    st4(out_e + ge * 128 + c0 + 4, make_float4(val[4], val[5], val[6], val[7]));
  }
  // red aliases et (dead; reduce has leading sync)
  col_stats_reduce(et, csum, csq, cg, rg, tid, bn_sum, bn_sq);
}

// ---------------------------------------------------------------------------
// CSR build: histogram -> 3-phase exclusive scan -> scatter edge ids
// ---------------------------------------------------------------------------
__global__ void k_hist(const int* __restrict__ dst, int* __restrict__ cnt)
{
  int t = blockIdx.x * blockDim.x + threadIdx.x;
  if (t < NE) atomicAdd(&cnt[dst[t]], 1);
}

__global__ __launch_bounds__(256) void k_scan1(const int* __restrict__ cnt,
                                               int* __restrict__ incl, int* __restrict__ partial)
{
  __shared__ int buf[256];
  int t = blockIdx.x * 256 + threadIdx.x;
  int v = (t < NN) ? cnt[t] : 0;
  buf[threadIdx.x] = v;
  __syncthreads();
  for (int ofs = 1; ofs < 256; ofs <<= 1) {
    int add = (threadIdx.x >= ofs) ? buf[threadIdx.x - ofs] : 0;
    __syncthreads();
    buf[threadIdx.x] += add;
    __syncthreads();
  }
  incl[t] = buf[threadIdx.x];
  if (threadIdx.x == 255) partial[blockIdx.x] = buf[255];
}

__global__ __launch_bounds__(256) void k_scan2(int* __restrict__ partial)
{
  __shared__ int buf[256];
  int v = (threadIdx.x < SCAN_CHUNKS) ? partial[threadIdx.x] : 0;
  buf[threadIdx.x] = v;
  __syncthreads();
  for (int ofs = 1; ofs < 256; ofs <<= 1) {
    int add = (threadIdx.x >= ofs) ? buf[threadIdx.x - ofs] : 0;
    __syncthreads();
    buf[threadIdx.x] += add;
    __syncthreads();
  }
  if (threadIdx.x < SCAN_CHUNKS) partial[threadIdx.x] = buf[threadIdx.x];
}

__global__ __launch_bounds__(256) void k_scan3(const int* __restrict__ cnt, const int* __restrict__ incl,
                                               const int* __restrict__ partial,
                                               int* __restrict__ off, int* __restrict__ cursor)
{
  int t = blockIdx.x * 256 + threadIdx.x;
  if (t < NN) {
    int base = (blockIdx.x > 0) ? partial[blockIdx.x - 1] : 0;
    int excl = base + incl[t] - cnt[t];
    off[t] = excl;
    cursor[t] = excl;
  }
  if (t == 0) off[NN] = NE;
}

__global__ void k_scatter(const int* __restrict__ dst, int* __restrict__ cursor, int* __restrict__ eidx)
{
  int t = blockIdx.x * blockDim.x + threadIdx.x;
  if (t < NE) {
    int pos = atomicAdd(&cursor[dst[t]], 1);
    eidx[pos] = t;
  }
}

// ---------------------------------------------------------------------------
// Gather: per node n, 128 threads (one per col) walk CSR edge list:
// hA[n][c] = (sum_e V[src_e][c] * s_e,head(c)) / (sum_e s_e,head(c) + 1e-6)
// No atomics. 2 nodes per 256-thread block.
// ---------------------------------------------------------------------------
__global__ __launch_bounds__(256) void k_gather(
    const float* __restrict__ V, const float* __restrict__ s_buf,
    const int* __restrict__ off, const int* __restrict__ eidx, const int* __restrict__ src,
    float* __restrict__ hA)
{
  const int g = threadIdx.x >> 7;
  const int c = threadIdx.x & 127;
  const int n = blockIdx.x * 2 + g;
  const int head = c >> 4;
  const int base = off[n], end = off[n + 1];

  float acc = 0.f, zacc = 0.f;
  int i = base;
  if (i < end) {
    int e = eidx[i];
    float sv = s_buf[(size_t)e * 8 + head];
    int sn = src[e];
    for (++i; i < end; ++i) {
      int e2 = eidx[i];
      float sv2 = s_buf[(size_t)e2 * 8 + head];
      int sn2 = src[e2];
      acc = fmaf(V[(size_t)sn * 128 + c], sv, acc);
      zacc += sv;
      e = e2; sv = sv2; sn = sn2;
    }
    acc = fmaf(V[(size_t)sn * 128 + c], sv, acc);
    zacc += sv;
  }
  hA[(size_t)n * 128 + c] = acc / (zacc + 1e-6f);
}

// ---------------------------------------------------------------------------
// Node kernel: h2 = h + hA@O_h_w + O_h_b -> out_h (hA lives in out_h region;
// block reads its rows into LDS before overwriting them)
// ---------------------------------------------------------------------------
__global__ __launch_bounds__(256) void k_node(
    const float* __restrict__ h, const float* __restrict__ hA,
    const float* __restrict__ Ohw, const float* __restrict__ Ohb,
    float* __restrict__ out_h, double* __restrict__ bn_sum, double* __restrict__ bn_sq)
{
  __shared__ float At[64 * 132];
  __shared__ float red[16 * 128];
  const int tid = threadIdx.x;
  const int r0 = blockIdx.x * 64;

#pragma unroll
  for (int i = 0; i < 8; ++i) {
    int lin = tid + i * 256;
    int row = lin >> 5, c4 = (lin & 31) * 4;
    int gr = r0 + row;
    float4 v = make_float4(0.f, 0.f, 0.f, 0.f);
    if (gr < NN) v = ld4(hA + (size_t)gr * 128 + c4);
    st4(At + row * 132 + c4, v);
  }
  __syncthreads();
  const int cg = tid & 15, rg = tid >> 4;
  const int c0 = cg * 8;
  float acc[4][8] = {};
  gemm_f32<4, 128, 132>(At, Ohw, 128, 0, cg, rg, acc);

  float bias[8];
#pragma unroll
  for (int j = 0; j < 8; ++j) bias[j] = Ohb[c0 + j];

  float csum[8] = {}, csq[8] = {};
#pragma unroll
  for (int r = 0; r < 4; ++r) {
    int row = r0 + rg + 16 * r;
    if (row < NN) {
      float4 h1 = ld4(h + (size_t)row * 128 + c0), h2 = ld4(h + (size_t)row * 128 + c0 + 4);
      float hv[8] = {h1.x, h1.y, h1.z, h1.w, h2.x, h2.y, h2.z, h2.w};
      float val[8];
#pragma unroll
      for (int j = 0; j < 8; ++j) {
        val[j] = hv[j] + acc[r][j] + bias[j];
        csum[j] += val[j];
        csq[j] += val[j] * val[j];
      }
      st4(out_h + (size_t)row * 128 + c0,     make_float4(val[0], val[1], val[2], val[3]));
      st4(out_h + (size_t)row * 128 + c0 + 4, make_float4(val[4], val[5], val[6], val[7]));
    }
  }
  col_stats_reduce(red, csum, csq, cg, rg, tid, bn_sum, bn_sq);
}

// ---------------------------------------------------------------------------
// BN finalize: scale = g*rsqrt(var+eps), shift = b - mean*scale  (h set + e set)
// ---------------------------------------------------------------------------
__global__ void k_bnfin(const double* sum_h, const double* sq_h,
                        const float* g_h, const float* b_h, float cnt_h,
                        float* sc_h, float* sh_h,
                        const double* sum_e, const double* sq_e,
                        const float* g_e, const float* b_e, float cnt_e,
                        float* sc_e, float* sh_e)
{
  int t = threadIdx.x;
  if (t < 128) {
    float m = (float)(sum_h[t] / (double)cnt_h);
    float v = (float)(sq_h[t] / (double)cnt_h) - m * m;
    float is = 1.f / sqrtf(v + 1e-5f);
    float s = is * g_h[t];
    sc_h[t] = s; sh_h[t] = b_h[t] - m * s;
  } else if (t < 256) {
    int c = t - 128;
    float m = (float)(sum_e[c] / (double)cnt_e);
    float v = (float)(sq_e[c] / (double)cnt_e) - m * m;
    float is = 1.f / sqrtf(v + 1e-5f);
    float s = is * g_e[c];
    sc_e[c] = s; sh_e[c] = b_e[c] - m * s;
  }
}

// ---------------------------------------------------------------------------
// FFN: x = BN1(row); t = x + relu(x@W1+b1)@W2+b2  (in-place on io) + bn2 stats
// 32-row tiles. red aliases ut -> LDS ~50 KB -> 3 blocks/CU.
// ---------------------------------------------------------------------------
__global__ __launch_bounds__(256) void k_ffn(
    float* __restrict__ io,
    const float* __restrict__ sc1, const float* __restrict__ sh1,
    const float* __restrict__ W1, const float* __restrict__ b1,
    const float* __restrict__ W2, const float* __restrict__ b2,
    double* __restrict__ bn_sum, double* __restrict__ bn_sq, int Rtot)
{
  __shared__ float xt[32 * 132];
  __shared__ float ut[32 * 260];
  const int tid = threadIdx.x;
  const int r0 = blockIdx.x * 32;

#pragma unroll
  for (int i = 0; i < 4; ++i) {
    int lin = tid + i * 256;
    int row = lin >> 5, c4 = (lin & 31) * 4;
    int gr = r0 + row;
    float4 v = make_float4(0.f, 0.f, 0.f, 0.f);
    if (gr < Rtot) {
      float4 x = ld4(io + (size_t)gr * 128 + c4);
      float4 s = ld4(sc1 + c4), sh = ld4(sh1 + c4);
      v = make_float4(fmaf(x.x, s.x, sh.x), fmaf(x.y, s.y, sh.y),
                      fmaf(x.z, s.z, sh.z), fmaf(x.w, s.w, sh.w));
    }
    st4(xt + row * 132 + c4, v);
  }
  __syncthreads();
  const int cg = tid & 15, rg = tid >> 4;
  const int c0 = cg * 8;

  // GEMM1: u = relu(x@W1 + b1), 256 cols in two halves
#pragma unroll 1
  for (int ch = 0; ch < 2; ++ch) {
    float acc[2][8] = {};
    gemm_f32<2, 128, 132>(xt, W1, 256, ch * 128, cg, rg, acc);
#pragma unroll
    for (int r = 0; r < 2; ++r) {
      int lrow = rg + 16 * r;
#pragma unroll
      for (int j = 0; j < 8; ++j) {
        float uv = acc[r][j] + b1[ch * 128 + c0 + j];
        ut[lrow * 260 + ch * 128 + c0 + j] = fmaxf(uv, 0.f);
      }
    }
  }
  __syncthreads();

  // GEMM2: t = x + u@W2 + b2
  float acc[2][8] = {};
  gemm_f32<2, 256, 260>(ut, W2, 128, 0, cg, rg, acc);

  float bias[8];
#pragma unroll
  for (int j = 0; j < 8; ++j) bias[j] = b2[c0 + j];

  float csum[8] = {}, csq[8] = {};
#pragma unroll
  for (int r = 0; r < 2; ++r) {
    int lrow = rg + 16 * r;
    int gr = r0 + lrow;
    if (gr < Rtot) {
      float val[8];
#pragma unroll
      for (int j = 0; j < 8; ++j) {
        val[j] = xt[lrow * 132 + c0 + j] + acc[r][j] + bias[j];
        csum[j] += val[j];
        csq[j] += val[j] * val[j];
      }
      st4(io + (size_t)gr * 128 + c0,     make_float4(val[0], val[1], val[2], val[3]));
      st4(io + (size_t)gr * 128 + c0 + 4, make_float4(val[4], val[5], val[6], val[7]));
    }
  }
  // red aliases ut (dead after GEMM2; reduce has leading sync)
  col_stats_reduce(ut, csum, csq, cg, rg, tid, bn_sum, bn_sq);
}

// ---------------------------------------------------------------------------
// Final BN apply for both h and e ranges (in place, elementwise), one launch
// ---------------------------------------------------------------------------
__global__ void k_bnapply2(float* __restrict__ oh, float* __restrict__ oe,
                           const float* __restrict__ sch, const float* __restrict__ shh,
                           const float* __restrict__ sce, const float* __restrict__ she)
{
  const int n4h = NN * 32;
  const int n4t = (NN + NE) * 32;
  for (int i = blockIdx.x * blockDim.x + threadIdx.x; i < n4t; i += gridDim.x * blockDim.x) {
    int c4 = (i & 31) * 4;
    float* p;
    const float* sc;
    const float* sh;
    if (i < n4h) { p = oh + (size_t)i * 4; sc = sch; sh = shh; }
    else { p = oe + (size_t)(i - n4h) * 4; sc = sce; sh = she; }
    float4 v = ld4(p);
    float4 s = ld4(sc + c4), b = ld4(sh + c4);
    st4(p, make_float4(fmaf(v.x, s.x, b.x), fmaf(v.y, s.y, b.y),
                       fmaf(v.z, s.z, b.z), fmaf(v.w, s.w, b.w)));
  }
}

// ---------------------------------------------------------------------------
extern "C" void kernel_launch(void* const* d_in, const int* in_sizes, int n_in,
                              void* d_out, int out_size, void* d_ws, size_t ws_size,
                              hipStream_t stream)
{
  const float* h    = (const float*)d_in[0];
  const float* e    = (const float*)d_in[1];
  const float* Wq   = (const float*)d_in[2];
  const float* Wk   = (const float*)d_in[3];
  const float* Wv   = (const float*)d_in[4];
  const float* We   = (const float*)d_in[5];
  const float* Ohw  = (const float*)d_in[6];
  const float* Ohb  = (const float*)d_in[7];
  const float* Oew  = (const float*)d_in[8];
  const float* Oeb  = (const float*)d_in[9];
  const float* bn1h_g = (const float*)d_in[10];
  const float* bn1h_b = (const float*)d_in[11];
  const float* bn1e_g = (const float*)d_in[12];
  const float* bn1e_b = (const float*)d_in[13];
  const float* fhw1 = (const float*)d_in[14];
  const float* fhb1 = (const float*)d_in[15];
  const float* fhw2 = (const float*)d_in[16];
  const float* fhb2 = (const float*)d_in[17];
  const float* few1 = (const float*)d_in[18];
  const float* feb1 = (const float*)d_in[19];
  const float* few2 = (const float*)d_in[20];
  const float* feb2 = (const float*)d_in[21];
  const float* bn2h_g = (const float*)d_in[22];
  const float* bn2h_b = (const float*)d_in[23];
  const float* bn2e_g = (const float*)d_in[24];
  const float* bn2e_b = (const float*)d_in[25];
  const int* src = (const int*)d_in[26];
  const int* dst = (const int*)d_in[27];

  float* out_h = (float*)d_out;                       // hA scratch, then h3
  float* out_e = (float*)d_out + (size_t)NN * 128;    // pre-BN scratch, then e3

  float* ws = (float*)d_ws;
  float* Q     = ws;
  float* Kp    = Q  + (size_t)NN * 128;
  float* Vp    = Kp + (size_t)NN * 128;
  float* s_buf = Vp + (size_t)NN * 128;               // [NE*8]
  double* stats = (double*)(s_buf + (size_t)NE * 8);  // 1024 doubles (8B-aligned)
  double* bn1h_sum = stats;        double* bn1h_sq = stats + 128;
  double* bn1e_sum = stats + 256;  double* bn1e_sq = stats + 384;
  double* bn2h_sum = stats + 512;  double* bn2h_sq = stats + 640;
  double* bn2e_sum = stats + 768;  double* bn2e_sq = stats + 896;
  int* cnt     = (int*)(stats + 1024);                // [NN]
  int* off     = cnt + NN;                            // [NN+1]
  int* cursor  = off + NN + 1;                        // [NN]
  int* incl    = cursor + NN;                         // [SCAN_CHUNKS*256]
  int* partial = incl + SCAN_CHUNKS * 256;            // [256]
  int* eidx    = partial + 256;                       // [NE]
  float* par   = (float*)(eidx + NE);                 // 1024 floats
  float* sc1h = par;        float* sh1h = par + 128;
  float* sc1e = par + 256;  float* sh1e = par + 384;
  float* sc2h = par + 512;  float* sh2h = par + 640;
  float* sc2e = par + 768;  float* sh2e = par + 896;

  // zero stats (1024 doubles) + cnt (NN ints) — contiguous
  hipMemsetAsync(stats, 0, 1024 * sizeof(double) + (size_t)NN * sizeof(int), stream);

  const int nb_n64 = (NN + 63) / 64;       // 782
  const int nb_e64 = NE / 64;              // 12500
  const int nb_e256 = (NE + 255) / 256;    // 3125
  const int nb_n32 = (NN + 31) / 32;       // 1563
  const int nb_e32 = NE / 32;              // 25000

  k_qkv<<<nb_n64, 256, 0, stream>>>(h, Wq, Wk, Wv, Q, Kp, Vp);

  // CSR build
  k_hist<<<nb_e256, 256, 0, stream>>>(dst, cnt);
  k_scan1<<<SCAN_CHUNKS, 256, 0, stream>>>(cnt, incl, partial);
  k_scan2<<<1, 256, 0, stream>>>(partial);
  k_scan3<<<SCAN_CHUNKS, 256, 0, stream>>>(cnt, incl, partial, off, cursor);
  k_scatter<<<nb_e256, 256, 0, stream>>>(dst, cursor, eidx);

  k_edge<<<nb_e64, 256, 0, stream>>>(e, We, Oew, Oeb, Q, Kp, src, dst,
                                     s_buf, out_e, bn1e_sum, bn1e_sq);

  k_gather<<<NN / 2, 256, 0, stream>>>(Vp, s_buf, off, eidx, src, out_h);

  k_node<<<nb_n64, 256, 0, stream>>>(h, out_h, Ohw, Ohb, out_h, bn1h_sum, bn1h_sq);

  k_bnfin<<<1, 256, 0, stream>>>(bn1h_sum, bn1h_sq, bn1h_g, bn1h_b, (float)NN, sc1h, sh1h,
                                 bn1e_sum, bn1e_sq, bn1e_g, bn1e_b, (float)NE, sc1e, sh1e);

  k_ffn<<<nb_n32, 256, 0, stream>>>(out_h, sc1h, sh1h, fhw1, fhb1, fhw2, fhb2,
                                    bn2h_sum, bn2h_sq, NN);
  k_ffn<<<nb_e32, 256, 0, stream>>>(out_e, sc1e, sh1e, few1, feb1, few2, feb2,
                                    bn2e_sum, bn2e_sq, NE);

  k_bnfin<<<1, 256, 0, stream>>>(bn2h_sum, bn2h_sq, bn2h_g, bn2h_b, (float)NN, sc2h, sh2h,
                                 bn2e_sum, bn2e_sq, bn2e_g, bn2e_b, (float)NE, sc2e, sh2e);

  k_bnapply2<<<2048, 256, 0, stream>>>(out_h, out_e, sc2h, sh2h, sc2e, sh2e);
}